// Round 7
// baseline (532.245 us; speedup 1.0000x reference)
//
#include <hip/hip_runtime.h>
#include <math.h>

#define NB 8
#define NP 19248
#define NC 81
#define NOBJ 8
#define NK 32
#define PHD 138
#define PWD 138
#define NPX (PHD * PWD)   // 19044
#define IH 550
#define IW 550
#define NBLK 76           // ceil(NP/256)
#define MROWG 9624        // (NB*NP)/16 row-groups for mark
#define MG2 512           // mark virtual chunks in P2
#define BFSTRIDE 80       // blkfmax row stride (u64)
#define FGRID 512         // fused grid: 2 blocks/CU x 256 CUs, co-residency guaranteed

__device__ __forceinline__ float wave_sum(float v) {
  #pragma unroll
  for (int o = 32; o >= 1; o >>= 1) v += __shfl_xor(v, o);
  return v;
}
__device__ __forceinline__ int wave_sum_i(int v) {
  #pragma unroll
  for (int o = 32; o >= 1; o >>= 1) v += __shfl_xor(v, o);
  return v;
}

// Grid barrier. Safe because FGRID=512 blocks are guaranteed co-resident
// (launch_bounds(256,2): VGPR<=256, LDS 28KB<=80KB -> >=2 blocks/CU).
// Release: syncthreads (drains all waves' stores to L2) + threadfence (wbL2).
// Acquire: spin on agent-scope atomic load + threadfence in all threads (inv).
__device__ __forceinline__ void gbar(int* bar, int ph) {
  __syncthreads();
  if (threadIdx.x == 0) {
    __threadfence();
    atomicAdd(&bar[ph * 16], 1);
    while (__hip_atomic_load(&bar[ph * 16], __ATOMIC_RELAXED,
                             __HIP_MEMORY_SCOPE_AGENT) < FGRID)
      __builtin_amdgcn_s_sleep(2);
  }
  __syncthreads();
  __threadfence();
}

__global__ __launch_bounds__(256, 2) void fused_kernel(
    const float* class_p, const float* box_p, const float* coef_p,
    const float* proto_p, const float* priors, const float* box_gt,
    const float* mask_gt, const int* class_gt,
    float* prior_max, int* prior_arg, int* conf_arr, float* marks,
    unsigned char* dmp, int* pos_list, int* npos_arr, int* nneg_arr,
    float* scale_arr, float* blkloss, int* blkcnt,
    float* accum, int* gtot, float* asp, int* bar, float* out)
{
  const int bid = blockIdx.x, tid = threadIdx.x;
  const int lane = tid & 63, wv = tid >> 6;
  unsigned long long* blkfmax = (unsigned long long*)marks;  // alias: dead until mark (P2)

  __shared__ float s_gx1[NOBJ], s_gy1[NOBJ], s_gx2[NOBJ], s_gy2[NOBJ], s_ga[NOBJ];
  __shared__ unsigned long long s_red[4][NOBJ];
  __shared__ int s_fi[NOBJ];
  __shared__ float s_f4[4];
  __shared__ int s_i4[4];
  __shared__ int s_pre;
  __shared__ unsigned s_lo, s_hi;
  __shared__ float r_tmp[4][IW];
  __shared__ float r_wx[PWD][9];
  __shared__ float r_wsx[PWD];
  __shared__ int   r_xlo[PWD];
  __shared__ int m_klist[100];
  __shared__ int m_kn;
  __shared__ float m_cf[100 * NK];

  const float C_POS   = 16.11809565f;     // -log(1e-7)
  const float C_NEGHI = 15.94238515f;     // -log1p(-0.99999988f)
  const float C_NEGLO = 1.00000005e-07f;  // -log1p(-1e-7f)

  // ================= P0: match1 (608 vb) || resize (368 vb) =================
  for (int vb = bid; vb < NB * NBLK + 368; vb += FGRID) {
    if (vb < NB * NBLK) {
      // ---- match1 ----
      int b = vb / NBLK, bx = vb - b * NBLK;
      int p = bx * 256 + tid;
      if (tid < NOBJ) {
        const float* g = box_gt + (b * NOBJ + tid) * 4;
        float x1 = g[0], y1 = g[1], x2 = g[2], y2 = g[3];
        s_gx1[tid] = x1; s_gy1[tid] = y1; s_gx2[tid] = x2; s_gy2[tid] = y2;
        s_ga[tid] = (x2 - x1) * (y2 - y1);
      }
      __syncthreads();
      bool act = p < NP;
      float dx1 = 0, dy1 = 0, dx2 = 0, dy2 = 0, darea = 1.f;
      if (act) {
        const float* pr = priors + p * 4;
        float cx = pr[0], cy = pr[1], w = pr[2], h = pr[3];
        dx1 = cx - w * 0.5f; dy1 = cy - h * 0.5f;
        dx2 = cx + w * 0.5f; dy2 = cy + h * 0.5f;
        darea = (dx2 - dx1) * (dy2 - dy1);
      }
      float pmax = -1.f; int parg = 0;
      unsigned long long pk[NOBJ];
      #pragma unroll
      for (int j = 0; j < NOBJ; j++) {
        float ix = fmaxf(fminf(s_gx2[j], dx2) - fmaxf(s_gx1[j], dx1), 0.f);
        float iy = fmaxf(fminf(s_gy2[j], dy2) - fmaxf(s_gy1[j], dy1), 0.f);
        float inter = ix * iy;
        float iou = inter / (s_ga[j] + darea - inter);
        if (j == 0) { pmax = iou; parg = 0; }
        else if (iou > pmax) { pmax = iou; parg = j; }   // strict >
        pk[j] = act ? ((((unsigned long long)__float_as_uint(iou)) << 32)
                       | (unsigned long long)(0x7fffffffu - (unsigned)p))
                    : 0ull;
      }
      if (act) {
        prior_max[b * NP + p] = pmax;
        prior_arg[b * NP + p] = parg;
      }
      #pragma unroll
      for (int j = 0; j < NOBJ; j++) {
        unsigned long long v = pk[j];
        #pragma unroll
        for (int o = 32; o >= 1; o >>= 1) {
          unsigned long long ov = __shfl_xor(v, o);
          if (ov > v) v = ov;
        }
        if (lane == 0) s_red[wv][j] = v;
      }
      __syncthreads();
      if (tid < NOBJ) {
        unsigned long long v = s_red[0][tid];
        #pragma unroll
        for (int w = 1; w < 4; w++) { unsigned long long t = s_red[w][tid]; if (t > v) v = t; }
        blkfmax[(size_t)(b * NOBJ + tid) * BFSTRIDE + bx] = v;
      }
      __syncthreads();   // protect s_gx*/s_red reuse on next vb
    } else {
      // ---- resize (one plane per wave, 6 output rows) ----
      int vb2 = vb - NB * NBLK;
      int pg = vb2 & 15;
      int oyg = vb2 >> 4;   // 0..22
      int bn = pg * 4 + wv;
      const float ks = (float)IH / (float)PHD;
      if (tid < PWD) {
        int ox = tid;
        float sx = (ox + 0.5f) * ks - 0.5f;
        int xlo = (int)ceilf(sx - ks); if (xlo < 0) xlo = 0;
        int xhi = (int)floorf(sx + ks); if (xhi > IW - 1) xhi = IW - 1;
        int nx = xhi - xlo;
        float wsx = 0.f;
        #pragma unroll
        for (int i = 0; i < 8; i++) {
          float w = (i <= nx) ? fmaxf(0.f, 1.f - fabsf(sx - (float)(xlo + i)) / ks) : 0.f;
          r_wx[ox][i] = w; wsx += w;
        }
        r_xlo[ox] = xlo;
        r_wsx[ox] = wsx;
      }
      __syncthreads();
      const float* mg = mask_gt + (size_t)bn * (IH * IW);
      int ones = 0;
      for (int q = 0; q < 6; ++q) {
        int oy = oyg * 6 + q;
        float sy = (oy + 0.5f) * ks - 0.5f;
        int ylo = (int)ceilf(sy - ks); if (ylo < 0) ylo = 0;
        int yhi = (int)floorf(sy + ks); if (yhi > IH - 1) yhi = IH - 1;
        int ny = yhi - ylo;
        float wy[8]; float wsy = 0.f;
        #pragma unroll
        for (int j = 0; j < 8; j++) {
          float w = (j <= ny) ? fmaxf(0.f, 1.f - fabsf(sy - (float)(ylo + j)) / ks) : 0.f;
          wy[j] = w; wsy += w;
        }
        const float* rowp[8];
        #pragma unroll
        for (int j = 0; j < 8; j++) {
          int y = ylo + j; if (y > IH - 1) y = IH - 1;
          rowp[j] = mg + (size_t)y * IW;
        }
        for (int x2 = lane; x2 < IW / 2; x2 += 64) {
          float ax = 0.f, ay = 0.f;
          #pragma unroll
          for (int j = 0; j < 8; j++) {
            float2 v = *(const float2*)(rowp[j] + 2 * x2);
            ax += wy[j] * v.x;
            ay += wy[j] * v.y;
          }
          r_tmp[wv][2 * x2]     = ax;
          r_tmp[wv][2 * x2 + 1] = ay;
        }
        __syncthreads();
        unsigned char* op = dmp + (size_t)bn * NPX + (size_t)oy * PWD;
        for (int ox = lane; ox < PWD; ox += 64) {
          int xlo = r_xlo[ox];
          float vsum = 0.f;
          #pragma unroll
          for (int i = 0; i < 8; i++) {
            int xi = xlo + i; if (xi > IW - 1) xi = IW - 1;
            vsum += r_wx[ox][i] * r_tmp[wv][xi];
          }
          int bit = (vsum > 0.5f * wsy * r_wsx[ox]) ? 1 : 0;
          op[ox] = (unsigned char)bit;
          ones += bit;
        }
        __syncthreads();
      }
      ones = wave_sum_i(ones);
      if (lane == 0) atomicAdd(&gtot[bn], ones);
    }
  }
  gbar(bar, 0);

  // ================= P1: conf (608 vb) =================
  for (int vb = bid; vb < NB * NBLK; vb += FGRID) {
    int b = vb / NBLK, bx = vb - b * NBLK;
    int p = bx * 256 + tid;
    // wave wv reduces boxes j = wv*2, wv*2+1 over the 76 block maxima
    #pragma unroll
    for (int jj = 0; jj < 2; jj++) {
      int j = wv * 2 + jj;
      const unsigned long long* bp_ = blkfmax + (size_t)(b * NOBJ + j) * BFSTRIDE;
      unsigned long long v = (lane < NBLK) ? bp_[lane] : 0ull;
      if (lane + 64 < NBLK) { unsigned long long t = bp_[lane + 64]; if (t > v) v = t; }
      #pragma unroll
      for (int o = 32; o >= 1; o >>= 1) {
        unsigned long long ov = __shfl_xor(v, o);
        if (ov > v) v = ov;
      }
      if (lane == 0) s_fi[j] = 0x7fffffff - (int)(v & 0xffffffffull);
    }
    __syncthreads();
    float lb = 0.f;
    bool flag = false;
    if (p < NP) {
      float m = prior_max[b * NP + p];
      int j = prior_arg[b * NP + p];
      int ov = -1;
      #pragma unroll
      for (int jj = 0; jj < NOBJ; jj++)
        if (p == s_fi[jj]) ov = jj;      // later j wins
      if (ov >= 0) { m = 2.0f; j = ov; prior_arg[b * NP + p] = ov; }
      int cf = class_gt[b * NOBJ + j] + 1;
      if (m < 0.5f) cf = -1;
      if (m < 0.4f) cf = 0;
      conf_arr[b * NP + p] = cf;
      flag = cf > 0;
      if (flag) {
        const float* g = box_gt + (b * NOBJ + j) * 4;
        float x1 = g[0], y1 = g[1], x2 = g[2], y2 = g[3];
        const float* pr = priors + p * 4;
        float pcx = pr[0], pcy = pr[1], prw = pr[2], prh = pr[3];
        float o4[4];
        o4[0] = ((x1 + x2) * 0.5f - pcx) / (0.1f * prw);
        o4[1] = ((y1 + y2) * 0.5f - pcy) / (0.1f * prh);
        o4[2] = logf((x2 - x1) / prw) / 0.2f;
        o4[3] = logf((y2 - y1) / prh) / 0.2f;
        const float* bp = box_p + (b * NP + p) * 4;
        #pragma unroll
        for (int c = 0; c < 4; c++) {
          float d = fabsf(bp[c] - o4[c]);
          lb += (d < 1.f) ? 0.5f * d * d : d - 0.5f;
        }
      }
    }
    unsigned long long bm = __ballot(flag);
    lb = wave_sum(lb);
    if (lane == 0) { s_f4[wv] = lb; s_i4[wv] = __popcll(bm); }
    __syncthreads();
    if (tid == 0) {
      blkloss[b * NBLK + bx] = s_f4[0] + s_f4[1] + s_f4[2] + s_f4[3];
      blkcnt[b * NBLK + bx] = s_i4[0] + s_i4[1] + s_i4[2] + s_i4[3];
    }
    __syncthreads();   // protect s_fi/s_f4/s_i4 reuse on next vb
  }
  gbar(bar, 1);

  // ================= P2: scatter (608 vb) || mark (512 chunks) =================
  for (int vb = bid; vb < NB * NBLK + MG2; vb += FGRID) {
    if (vb < NB * NBLK) {
      // ---- scatter ----
      int b = vb / NBLK, bx = vb - b * NBLK;
      if (tid < 64) {
        int s = 0;
        if (tid < bx) s += blkcnt[b * NBLK + tid];
        int t2 = tid + 64;
        if (t2 < bx) s += blkcnt[b * NBLK + t2];
        s = wave_sum_i(s);
        if (tid == 0) s_pre = s;
      }
      int p = bx * 256 + tid;
      bool flag = (p < NP) && (conf_arr[b * NP + p] > 0);
      unsigned long long m = __ballot(flag);
      if (lane == 0) s_i4[wv] = __popcll(m);
      __syncthreads();
      int base = s_pre;
      for (int w = 0; w < wv; w++) base += s_i4[w];
      int idx = base + __popcll(m & ((1ull << lane) - 1ull));
      if (flag && idx < 128) pos_list[b * 128 + idx] = p;
      if (bx == NBLK - 1) {
        if (tid == 0) {
          int np = s_pre + s_i4[0] + s_i4[1] + s_i4[2] + s_i4[3];
          npos_arr[b] = np;
          int nn = 3 * np; if (nn > NP - 1) nn = NP - 1;
          nneg_arr[b] = nn;
          scale_arr[b] = (np > 100) ? (float)np / 100.0f : 1.0f;
        }
        if (tid < 64) {
          float s = (tid < NBLK) ? blkloss[b * NBLK + tid] : 0.f;
          if (tid + 64 < NBLK) s += blkloss[b * NBLK + tid + 64];
          s = wave_sum(s);
          if (tid == 0) atomicAdd(&accum[0], s);
        }
      }
      __syncthreads();   // protect s_pre/s_i4 reuse on next vb
    } else {
      // ---- mark chunk ----
      int mc = vb - NB * NBLK;     // 0..511
      int sub = lane & 15, grp = lane >> 4;
      float acc1 = 0.f;
      for (int gblk = mc; gblk < MROWG; gblk += MG2) {
        int row = gblk * 16 + wv * 4 + grp;
        const float* cp = class_p + (size_t)row * NC;
        float v[6];
        #pragma unroll
        for (int k = 0; k < 6; k++) {
          int c = sub + 16 * k;
          v[k] = (c < NC) ? cp[c] : -INFINITY;
        }
        float m = v[0];
        #pragma unroll
        for (int k = 1; k < 6; k++) m = fmaxf(m, v[k]);
        #pragma unroll
        for (int o = 1; o < 16; o <<= 1) m = fmaxf(m, __shfl_xor(m, o));
        float s = 0.f;
        #pragma unroll
        for (int k = 0; k < 6; k++) s += __expf(v[k] - m);
        #pragma unroll
        for (int o = 1; o < 16; o <<= 1) s += __shfl_xor(s, o);
        float lse = m + __logf(s);
        if (sub == 0) {
          int cf = conf_arr[row];
          marks[row] = (cf != 0) ? 0.f : (lse - v[0]);
          if (cf > 0) acc1 += lse - cp[cf];
        }
      }
      acc1 = wave_sum(acc1);
      if (lane == 0) s_f4[wv] = acc1;
      __syncthreads();
      if (tid == 0)
        atomicAdd(&asp[(mc & 7) * 16], s_f4[0] + s_f4[1] + s_f4[2] + s_f4[3]);
      __syncthreads();
    }
  }
  gbar(bar, 2);

  // ================= P3: select (blocks 0..7) || maskloss (blocks 8..511) =================
  if (bid < NB) {
    // ---- select: per-batch top-k marks sum via bit binary search ----
    int b = bid;
    float v[NBLK];
    #pragma unroll
    for (int i = 0; i < NBLK; i++) {
      int p = i * 256 + tid;
      v[i] = (p < NP) ? marks[b * NP + p] : 0.f;
    }
    int k = nneg_arr[b];
    if (tid == 0) { s_lo = 0u; s_hi = 0x7f800000u; }
    __syncthreads();
    while (true) {
      unsigned lo = s_lo, hi = s_hi;
      if (hi - lo <= 1u) break;
      unsigned mid = lo + ((hi - lo) >> 1);
      float fmid = __uint_as_float(mid);
      int cnt = 0;
      #pragma unroll
      for (int i = 0; i < NBLK; i++) cnt += (v[i] >= fmid) ? 1 : 0;
      cnt = wave_sum_i(cnt);
      if (lane == 0) s_i4[wv] = cnt;
      __syncthreads();
      if (tid == 0) {
        int tot = s_i4[0] + s_i4[1] + s_i4[2] + s_i4[3];
        if (tot >= k) s_lo = mid; else s_hi = mid;
      }
      __syncthreads();
    }
    float thr = __uint_as_float(s_lo);
    float s = 0.f;
    #pragma unroll
    for (int i = 0; i < NBLK; i++) if (v[i] >= thr) s += v[i];
    s = wave_sum(s);
    if (lane == 0) s_f4[wv] = s;
    __syncthreads();
    if (tid == 0) atomicAdd(&asp[(b & 7) * 16], s_f4[0] + s_f4[1] + s_f4[2] + s_f4[3]);
  } else {
    // ---- maskloss: per-(box, row-chunk), 1024 vbs over 504 blocks ----
    for (int vb = bid - NB; vb < NB * NOBJ * 16; vb += FGRID - NB) {
      int bg = vb >> 4;          // 0..63 = b*NOBJ + gi
      int b = bg >> 3, gi = bg & 7;
      int chunk = vb & 15;       // 0..15
      int np = npos_arr[b];
      int mb = np < 100 ? np : 100;
      if (tid == 0) m_kn = 0;
      __syncthreads();
      if (tid < mb) {
        int p = pos_list[b * 128 + tid];
        if (prior_arg[b * NP + p] == gi) {
          int slot = atomicAdd(&m_kn, 1);
          m_klist[slot] = p;
        }
      }
      __syncthreads();
      int kn = m_kn;
      if (kn == 0) continue;   // uniform (m_kn is shared)

      const float* g = box_gt + (b * NOBJ + gi) * 4;
      float bx1 = g[0], by1 = g[1], bx2 = g[2], by2 = g[3];
      float ax = bx1 * 138.f, bx = bx2 * 138.f;
      float x1 = fminf(ax, bx), x2 = fmaxf(ax, bx);
      x1 = fmaxf(x1 - 1.f, 0.f); x2 = fminf(x2 + 1.f, 138.f);
      float ay = by1 * 138.f, by_ = by2 * 138.f;
      float y1 = fminf(ay, by_), y2 = fmaxf(ay, by_);
      y1 = fmaxf(y1 - 1.f, 0.f); y2 = fminf(y2 + 1.f, 138.f);
      float inv = 1.f / ((bx2 - bx1) * (by2 - by1));
      int xs = (int)ceilf(x1), xe = (int)ceilf(x2);
      int ys = (int)ceilf(y1), ye = (int)ceilf(y2);
      if (xe < xs) xe = xs;
      if (ye < ys) ye = ys;

      for (int i = tid; i < kn * NK; i += 256) {
        int kk = i >> 5, c = i & 31;
        m_cf[i] = coef_p[((size_t)(b * NP) + m_klist[kk]) * NK + c];
      }
      __syncthreads();

      float knf = (float)kn;
      const float* protoB = proto_p + (size_t)b * NPX * NK;
      const unsigned char* dpl = dmp + (size_t)(b * NOBJ + gi) * NPX;

      float lsum = 0.f;
      for (int y = ys + chunk * 4 + wv; y < ye; y += 64) {
        const float* rowp = protoB + (size_t)y * PWD * NK;
        const unsigned char* rowg = dpl + y * PWD;
        for (int x = xs + lane; x < xe; x += 64) {
          const float4* pr = (const float4*)(rowp + (size_t)x * NK);
          float4 a0 = pr[0], a1 = pr[1], a2 = pr[2], a3 = pr[3];
          float4 a4 = pr[4], a5 = pr[5], a6 = pr[6], a7 = pr[7];
          int gbit = rowg[x];
          float base = gbit ? C_POS : C_NEGLO;
          float acc = -knf * base;
          for (int kk = 0; kk < kn; ++kk) {
            const float4* cf = (const float4*)&m_cf[kk * NK];
            float4 c0 = cf[0], c1 = cf[1], c2 = cf[2], c3 = cf[3];
            float4 c4 = cf[4], c5 = cf[5], c6 = cf[6], c7 = cf[7];
            float dot =
                a0.x*c0.x + a0.y*c0.y + a0.z*c0.z + a0.w*c0.w +
                a1.x*c1.x + a1.y*c1.y + a1.z*c1.z + a1.w*c1.w +
                a2.x*c2.x + a2.y*c2.y + a2.z*c2.z + a2.w*c2.w +
                a3.x*c3.x + a3.y*c3.y + a3.z*c3.z + a3.w*c3.w +
                a4.x*c4.x + a4.y*c4.y + a4.z*c4.z + a4.w*c4.w +
                a5.x*c5.x + a5.y*c5.y + a5.z*c5.z + a5.w*c5.w +
                a6.x*c6.x + a6.y*c6.y + a6.z*c6.z + a6.w*c6.w +
                a7.x*c7.x + a7.y*c7.y + a7.z*c7.z + a7.w*c7.w;
            float l = dot;
            float el = __expf(-fabsf(l));
            float sp = fmaxf(l, 0.f) + __logf(1.f + el);
            float t1 = fminf(sp - l, C_POS);
            float t2 = fminf(fmaxf(sp, C_NEGLO), C_NEGHI);
            acc += gbit ? t1 : t2;
          }
          lsum += acc;
        }
      }

      lsum = wave_sum(lsum);
      if (lane == 0) s_f4[wv] = lsum;
      __syncthreads();
      if (tid == 0) {
        float L = s_f4[0] + s_f4[1] + s_f4[2] + s_f4[3];
        if (chunk == 0) {
          int Gt = gtot[bg];
          L += knf * (C_POS * (float)Gt + C_NEGLO * (float)(NPX - Gt));
        }
        atomicAdd(&asp[128 + (bg & 7) * 16], L * inv * scale_arr[b]);
      }
      __syncthreads();   // protect m_* / s_f4 reuse on next vb
    }
  }
  gbar(bar, 3);

  // ================= P4: finalize =================
  if (bid == 0 && tid == 0) {
    float c1 = 0.f, c2 = 0.f;
    #pragma unroll
    for (int i = 0; i < 8; i++) { c1 += asp[i * 16]; c2 += asp[128 + i * 16]; }
    out[0] = 1.5f * accum[0] + c1 + c2 * (6.125f / (138.f * 138.f));
  }
}

extern "C" void kernel_launch(void* const* d_in, const int* in_sizes, int n_in,
                              void* d_out, int out_size, void* d_ws, size_t ws_size,
                              hipStream_t stream) {
  const float* class_p  = (const float*)d_in[0];
  const float* box_p    = (const float*)d_in[1];
  const float* coef_p   = (const float*)d_in[2];
  const float* proto_p  = (const float*)d_in[3];
  const float* priors   = (const float*)d_in[4];
  const float* box_gt   = (const float*)d_in[5];
  const float* mask_gt  = (const float*)d_in[6];
  const int*   class_gt = (const int*)d_in[7];

  char* ws = (char*)d_ws;
  float* prior_max = (float*)(ws + 0);                 // NB*NP f32 = 615936 B
  int*   prior_arg = (int*)(ws + 615936);              // NB*NP i32
  int*   conf      = (int*)(ws + 1231872);             // NB*NP i32
  float* marks     = (float*)(ws + 1847808);           // NB*NP f32 (aliases blkfmax)
  unsigned char* dmp = (unsigned char*)(ws + 2463744); // NB*NOBJ*NPX u8 = 1218816
  int*   pos_list  = (int*)(ws + 3682560);             // NB*128 i32 = 4096
  int*   npos_arr  = (int*)(ws + 3686656);             // NB i32
  int*   nneg_arr  = (int*)(ws + 3686688);             // NB i32
  float* scale_arr = (float*)(ws + 3686720);           // NB f32
  float* blkloss   = (float*)(ws + 3686752);           // NB*NBLK f32 = 2432
  int*   blkcnt    = (int*)(ws + 3689184);             // NB*NBLK i32 = 2432
  // ---- memset region: accum(64) + gtot(256) + asp(1024) + bar(256) = 1600 B ----
  float* accum     = (float*)(ws + 3691616);
  int*   gtot      = (int*)(ws + 3691680);
  float* asp       = (float*)(ws + 3691936);
  int*   bar       = (int*)(ws + 3692960);
  (void)in_sizes; (void)n_in; (void)out_size; (void)ws_size;

  hipMemsetAsync((void*)accum, 0, 1600, stream);

  fused_kernel<<<FGRID, 256, 0, stream>>>(
      class_p, box_p, coef_p, proto_p, priors, box_gt, mask_gt, class_gt,
      prior_max, prior_arg, conf, marks, dmp, pos_list, npos_arr, nneg_arr,
      scale_arr, blkloss, blkcnt, accum, gtot, asp, bar, (float*)d_out);
}

// Round 8
// 244.104 us; speedup vs baseline: 2.1804x; 2.1804x over previous
//
#include <hip/hip_runtime.h>
#include <math.h>

#define NB 8
#define NP 19248
#define NC 81
#define NOBJ 8
#define NK 32
#define PHD 138
#define PWD 138
#define NPX (PHD * PWD)   // 19044
#define IH 550
#define IW 550
#define NBLK 76           // ceil(NP/256)
#define MROWG 9624        // (NB*NP)/16 row-groups for mark
#define MGRID 1203        // mark virtual grid: 8 row-groups per block
#define BFSTRIDE 80       // blkfmax row stride (u64)

__device__ __forceinline__ float wave_sum(float v) {
  #pragma unroll
  for (int o = 32; o >= 1; o >>= 1) v += __shfl_xor(v, o);
  return v;
}
__device__ __forceinline__ int wave_sum_i(int v) {
  #pragma unroll
  for (int o = 32; o >= 1; o >>= 1) v += __shfl_xor(v, o);
  return v;
}

// ============ P0: match1 (blocks 0..607) || resize (blocks 608..975) ============
// Independent stages share one dispatch via blockIdx partition — full grids,
// no grid barriers (the round-7 coop-grid fusion capped occupancy at 25% and
// regressed 2x; kernel boundaries are the sync here).
__global__ __launch_bounds__(256) void p0_match_resize(
    const float* __restrict__ priors, const float* __restrict__ box_gt,
    const float* __restrict__ mask_gt,
    float* __restrict__ prior_max, int* __restrict__ prior_arg,
    unsigned long long* __restrict__ blkfmax,
    unsigned char* __restrict__ dmp, int* __restrict__ gtot)
{
  const int bid = blockIdx.x, tid = threadIdx.x;
  const int lane = tid & 63, wv = tid >> 6;

  if (bid < NB * NBLK) {
    // ---- match1: per-prior max/arg; per-gt per-BLOCK max -> plain store ----
    int b = bid / NBLK, bx = bid - b * NBLK;
    int p = bx * 256 + tid;
    __shared__ float gx1[NOBJ], gy1[NOBJ], gx2[NOBJ], gy2[NOBJ], garea[NOBJ];
    __shared__ unsigned long long s_red[4][NOBJ];
    if (tid < NOBJ) {
      const float* g = box_gt + (b * NOBJ + tid) * 4;
      float x1 = g[0], y1 = g[1], x2 = g[2], y2 = g[3];
      gx1[tid] = x1; gy1[tid] = y1; gx2[tid] = x2; gy2[tid] = y2;
      garea[tid] = (x2 - x1) * (y2 - y1);
    }
    __syncthreads();
    bool act = p < NP;
    float dx1 = 0, dy1 = 0, dx2 = 0, dy2 = 0, darea = 1.f;
    if (act) {
      const float* pr = priors + p * 4;
      float cx = pr[0], cy = pr[1], w = pr[2], h = pr[3];
      dx1 = cx - w * 0.5f; dy1 = cy - h * 0.5f;
      dx2 = cx + w * 0.5f; dy2 = cy + h * 0.5f;
      darea = (dx2 - dx1) * (dy2 - dy1);
    }
    float pmax = -1.f; int parg = 0;
    unsigned long long pk[NOBJ];
    #pragma unroll
    for (int j = 0; j < NOBJ; j++) {
      float ix = fmaxf(fminf(gx2[j], dx2) - fmaxf(gx1[j], dx1), 0.f);
      float iy = fmaxf(fminf(gy2[j], dy2) - fmaxf(gy1[j], dy1), 0.f);
      float inter = ix * iy;
      float iou = inter / (garea[j] + darea - inter);
      if (j == 0) { pmax = iou; parg = 0; }
      else if (iou > pmax) { pmax = iou; parg = j; }   // strict > tie-break
      pk[j] = act ? ((((unsigned long long)__float_as_uint(iou)) << 32)
                     | (unsigned long long)(0x7fffffffu - (unsigned)p))
                  : 0ull;
    }
    if (act) {
      prior_max[b * NP + p] = pmax;
      prior_arg[b * NP + p] = parg;
    }
    #pragma unroll
    for (int j = 0; j < NOBJ; j++) {
      unsigned long long v = pk[j];
      #pragma unroll
      for (int o = 32; o >= 1; o >>= 1) {
        unsigned long long ov = __shfl_xor(v, o);
        if (ov > v) v = ov;
      }
      if (lane == 0) s_red[wv][j] = v;
    }
    __syncthreads();
    if (tid < NOBJ) {
      unsigned long long v = s_red[0][tid];
      #pragma unroll
      for (int w = 1; w < 4; w++) { unsigned long long t = s_red[w][tid]; if (t > v) v = t; }
      blkfmax[(size_t)(b * NOBJ + tid) * BFSTRIDE + bx] = v;
    }
  } else {
    // ---- resize: one plane per wave, 6 output rows; counts 1-bits -> gtot ----
    int vb2 = bid - NB * NBLK;   // 0..367
    int pg = vb2 & 15;
    int oyg = vb2 >> 4;          // 0..22
    int bn = pg * 4 + wv;        // plane 0..63
    __shared__ float r_tmp[4][IW];
    __shared__ float r_wx[PWD][9];
    __shared__ float r_wsx[PWD];
    __shared__ int   r_xlo[PWD];
    const float ks = (float)IH / (float)PHD;
    if (tid < PWD) {
      int ox = tid;
      float sx = (ox + 0.5f) * ks - 0.5f;
      int xlo = (int)ceilf(sx - ks); if (xlo < 0) xlo = 0;
      int xhi = (int)floorf(sx + ks); if (xhi > IW - 1) xhi = IW - 1;
      int nx = xhi - xlo;
      float wsx = 0.f;
      #pragma unroll
      for (int i = 0; i < 8; i++) {
        float w = (i <= nx) ? fmaxf(0.f, 1.f - fabsf(sx - (float)(xlo + i)) / ks) : 0.f;
        r_wx[ox][i] = w; wsx += w;
      }
      r_xlo[ox] = xlo;
      r_wsx[ox] = wsx;
    }
    __syncthreads();
    const float* mg = mask_gt + (size_t)bn * (IH * IW);
    int ones = 0;
    for (int q = 0; q < 6; ++q) {
      int oy = oyg * 6 + q;
      float sy = (oy + 0.5f) * ks - 0.5f;
      int ylo = (int)ceilf(sy - ks); if (ylo < 0) ylo = 0;
      int yhi = (int)floorf(sy + ks); if (yhi > IH - 1) yhi = IH - 1;
      int ny = yhi - ylo;
      float wy[8]; float wsy = 0.f;
      #pragma unroll
      for (int j = 0; j < 8; j++) {
        float w = (j <= ny) ? fmaxf(0.f, 1.f - fabsf(sy - (float)(ylo + j)) / ks) : 0.f;
        wy[j] = w; wsy += w;
      }
      const float* rowp[8];
      #pragma unroll
      for (int j = 0; j < 8; j++) {
        int y = ylo + j; if (y > IH - 1) y = IH - 1;
        rowp[j] = mg + (size_t)y * IW;
      }
      for (int x2 = lane; x2 < IW / 2; x2 += 64) {
        float ax = 0.f, ay = 0.f;
        #pragma unroll
        for (int j = 0; j < 8; j++) {
          float2 v = *(const float2*)(rowp[j] + 2 * x2);
          ax += wy[j] * v.x;
          ay += wy[j] * v.y;
        }
        r_tmp[wv][2 * x2]     = ax;
        r_tmp[wv][2 * x2 + 1] = ay;
      }
      __syncthreads();
      unsigned char* op = dmp + (size_t)bn * NPX + (size_t)oy * PWD;
      for (int ox = lane; ox < PWD; ox += 64) {
        int xlo = r_xlo[ox];
        float vsum = 0.f;
        #pragma unroll
        for (int i = 0; i < 8; i++) {
          int xi = xlo + i; if (xi > IW - 1) xi = IW - 1;
          vsum += r_wx[ox][i] * r_tmp[wv][xi];
        }
        int bit = (vsum > 0.5f * wsy * r_wsx[ox]) ? 1 : 0;
        op[ox] = (unsigned char)bit;
        ones += bit;
      }
      __syncthreads();
    }
    ones = wave_sum_i(ones);
    if (lane == 0) atomicAdd(&gtot[bn], ones);
  }
}

// ============ P1: conf (608 blocks) ============
__global__ __launch_bounds__(256) void conf_kernel(
    const float* __restrict__ priors, const float* __restrict__ box_gt,
    const int* __restrict__ class_gt, const float* __restrict__ box_p,
    const float* __restrict__ prior_max, int* __restrict__ prior_arg,
    const unsigned long long* __restrict__ blkfmax,
    int* __restrict__ conf, int* __restrict__ blkcnt, float* __restrict__ blkloss)
{
  int b = blockIdx.y, bx = blockIdx.x, tid = threadIdx.x;
  int p = bx * 256 + tid;
  int lane = tid & 63, wid = tid >> 6;
  __shared__ int s_fi[NOBJ];
  __shared__ float lbw[4];
  __shared__ int pcw[4];
  #pragma unroll
  for (int jj = 0; jj < 2; jj++) {
    int j = wid * 2 + jj;
    const unsigned long long* bp_ = blkfmax + (size_t)(b * NOBJ + j) * BFSTRIDE;
    unsigned long long v = (lane < NBLK) ? bp_[lane] : 0ull;
    if (lane + 64 < NBLK) { unsigned long long t = bp_[lane + 64]; if (t > v) v = t; }
    #pragma unroll
    for (int o = 32; o >= 1; o >>= 1) {
      unsigned long long ov = __shfl_xor(v, o);
      if (ov > v) v = ov;
    }
    if (lane == 0) s_fi[j] = 0x7fffffff - (int)(v & 0xffffffffull);
  }
  __syncthreads();
  float lb = 0.f;
  bool flag = false;
  if (p < NP) {
    float m = prior_max[b * NP + p];
    int j = prior_arg[b * NP + p];
    int ov = -1;
    #pragma unroll
    for (int jj = 0; jj < NOBJ; jj++)
      if (p == s_fi[jj]) ov = jj;      // later j wins
    if (ov >= 0) { m = 2.0f; j = ov; prior_arg[b * NP + p] = ov; }
    int cf = class_gt[b * NOBJ + j] + 1;
    if (m < 0.5f) cf = -1;
    if (m < 0.4f) cf = 0;
    conf[b * NP + p] = cf;
    flag = cf > 0;
    if (flag) {
      const float* g = box_gt + (b * NOBJ + j) * 4;
      float x1 = g[0], y1 = g[1], x2 = g[2], y2 = g[3];
      const float* pr = priors + p * 4;
      float pcx = pr[0], pcy = pr[1], prw = pr[2], prh = pr[3];
      float o4[4];
      o4[0] = ((x1 + x2) * 0.5f - pcx) / (0.1f * prw);
      o4[1] = ((y1 + y2) * 0.5f - pcy) / (0.1f * prh);
      o4[2] = logf((x2 - x1) / prw) / 0.2f;
      o4[3] = logf((y2 - y1) / prh) / 0.2f;
      const float* bp = box_p + (b * NP + p) * 4;
      #pragma unroll
      for (int c = 0; c < 4; c++) {
        float d = fabsf(bp[c] - o4[c]);
        lb += (d < 1.f) ? 0.5f * d * d : d - 0.5f;
      }
    }
  }
  unsigned long long bm = __ballot(flag);
  lb = wave_sum(lb);
  if (lane == 0) { lbw[wid] = lb; pcw[wid] = __popcll(bm); }
  __syncthreads();
  if (tid == 0) {
    blkloss[b * NBLK + bx] = lbw[0] + lbw[1] + lbw[2] + lbw[3];
    blkcnt[b * NBLK + bx] = pcw[0] + pcw[1] + pcw[2] + pcw[3];
  }
}

// ============ P2: scatter (blocks 0..607) || mark (blocks 608..1810) ============
__global__ __launch_bounds__(256) void p2_scatter_mark(
    const float* __restrict__ class_p, const int* __restrict__ conf,
    const int* __restrict__ blkcnt, const float* __restrict__ blkloss,
    int* __restrict__ pos_list, int* __restrict__ npos_arr,
    int* __restrict__ nneg_arr, float* __restrict__ scale_arr,
    float* __restrict__ marks, float* __restrict__ accum, float* __restrict__ asp)
{
  const int bid = blockIdx.x, tid = threadIdx.x;
  const int lane = tid & 63, wid = tid >> 6;

  if (bid < NB * NBLK) {
    // ---- scatter: ordered compaction + per-batch totals + box-loss reduce ----
    int b = bid / NBLK, bx = bid - b * NBLK;
    __shared__ int s_pre;
    __shared__ int wc[4];
    if (tid < 64) {
      int s = 0;
      if (tid < bx) s += blkcnt[b * NBLK + tid];
      int t2 = tid + 64;
      if (t2 < bx) s += blkcnt[b * NBLK + t2];
      s = wave_sum_i(s);
      if (tid == 0) s_pre = s;
    }
    int p = bx * 256 + tid;
    bool flag = (p < NP) && (conf[b * NP + p] > 0);
    unsigned long long m = __ballot(flag);
    if (lane == 0) wc[wid] = __popcll(m);
    __syncthreads();
    int base = s_pre;
    for (int w = 0; w < wid; w++) base += wc[w];
    int idx = base + __popcll(m & ((1ull << lane) - 1ull));
    if (flag && idx < 128) pos_list[b * 128 + idx] = p;
    if (bx == NBLK - 1) {
      if (tid == 0) {
        int np = s_pre + wc[0] + wc[1] + wc[2] + wc[3];
        npos_arr[b] = np;
        int nn = 3 * np; if (nn > NP - 1) nn = NP - 1;
        nneg_arr[b] = nn;
        scale_arr[b] = (np > 100) ? (float)np / 100.0f : 1.0f;
      }
      if (tid < 64) {
        float s = (tid < NBLK) ? blkloss[b * NBLK + tid] : 0.f;
        if (tid + 64 < NBLK) s += blkloss[b * NBLK + tid + 64];
        s = wave_sum(s);
        if (tid == 0) atomicAdd(&accum[0], s);
      }
    }
  } else {
    // ---- mark: grid-stride LSE rows; block-level NLL -> spread atomic slots ----
    int mbid = bid - NB * NBLK;   // 0..1202
    int sub = lane & 15, grp = lane >> 4;
    __shared__ float sred[4];
    float acc1 = 0.f;
    for (int gblk = mbid; gblk < MROWG; gblk += MGRID) {
      int row = gblk * 16 + wid * 4 + grp;
      const float* cp = class_p + (size_t)row * NC;
      float v[6];
      #pragma unroll
      for (int k = 0; k < 6; k++) {
        int c = sub + 16 * k;
        v[k] = (c < NC) ? cp[c] : -INFINITY;
      }
      float m = v[0];
      #pragma unroll
      for (int k = 1; k < 6; k++) m = fmaxf(m, v[k]);
      #pragma unroll
      for (int o = 1; o < 16; o <<= 1) m = fmaxf(m, __shfl_xor(m, o));
      float s = 0.f;
      #pragma unroll
      for (int k = 0; k < 6; k++) s += __expf(v[k] - m);
      #pragma unroll
      for (int o = 1; o < 16; o <<= 1) s += __shfl_xor(s, o);
      float lse = m + __logf(s);
      if (sub == 0) {
        int cf = conf[row];
        marks[row] = (cf != 0) ? 0.f : (lse - v[0]);
        if (cf > 0) acc1 += lse - cp[cf];
      }
    }
    acc1 = wave_sum(acc1);
    if (lane == 0) sred[wid] = acc1;
    __syncthreads();
    if (tid == 0)
      atomicAdd(&asp[(mbid & 7) * 16], sred[0] + sred[1] + sred[2] + sred[3]);
  }
}

// ============ P3: select (blocks 0..7) || maskloss (blocks 8..1031) ============
__global__ __launch_bounds__(256) void p3_select_maskloss(
    const float* __restrict__ proto_p, const float* __restrict__ coef_p,
    const float* __restrict__ box_gt, const int* __restrict__ pmi,
    const unsigned char* __restrict__ dmp, const int* __restrict__ pos_list,
    const int* __restrict__ npos_arr, const int* __restrict__ nneg_arr,
    const int* __restrict__ gtot, const float* __restrict__ scale_arr,
    const float* __restrict__ marks, float* __restrict__ asp)
{
  const int bid = blockIdx.x, tid = threadIdx.x;
  const int lane = tid & 63, wv = tid >> 6;
  const float C_POS   = 16.11809565f;     // -log(1e-7)
  const float C_NEGHI = 15.94238515f;     // -log1p(-0.99999988f)
  const float C_NEGLO = 1.00000005e-07f;  // -log1p(-1e-7f)

  if (bid < NB) {
    // ---- select: per-batch top-k marks sum via bit-space binary search ----
    int b = bid;
    __shared__ unsigned s_lo, s_hi;
    __shared__ int s_i4[4];
    __shared__ float s_f4[4];
    float v[NBLK];
    #pragma unroll
    for (int i = 0; i < NBLK; i++) {
      int p = i * 256 + tid;
      v[i] = (p < NP) ? marks[b * NP + p] : 0.f;
    }
    int k = nneg_arr[b];
    if (tid == 0) { s_lo = 0u; s_hi = 0x7f800000u; }
    __syncthreads();
    while (true) {
      unsigned lo = s_lo, hi = s_hi;
      if (hi - lo <= 1u) break;
      unsigned mid = lo + ((hi - lo) >> 1);
      float fmid = __uint_as_float(mid);
      int cnt = 0;
      #pragma unroll
      for (int i = 0; i < NBLK; i++) cnt += (v[i] >= fmid) ? 1 : 0;
      cnt = wave_sum_i(cnt);
      if (lane == 0) s_i4[wv] = cnt;
      __syncthreads();
      if (tid == 0) {
        int tot = s_i4[0] + s_i4[1] + s_i4[2] + s_i4[3];
        if (tot >= k) s_lo = mid; else s_hi = mid;
      }
      __syncthreads();
    }
    float thr = __uint_as_float(s_lo);
    float s = 0.f;
    #pragma unroll
    for (int i = 0; i < NBLK; i++) if (v[i] >= thr) s += v[i];
    s = wave_sum(s);
    if (lane == 0) s_f4[wv] = s;
    __syncthreads();
    if (tid == 0) atomicAdd(&asp[(b & 7) * 16], s_f4[0] + s_f4[1] + s_f4[2] + s_f4[3]);
  } else {
    // ---- maskloss: per-(box, row-chunk) rect-only f32 dot + folded constants ----
    int vb = bid - NB;         // 0..1023
    int bg = vb >> 4;          // 0..63 = b*NOBJ + gi
    int b = bg >> 3, gi = bg & 7;
    int chunk = vb & 15;
    int np = npos_arr[b];
    int mb = np < 100 ? np : 100;

    __shared__ int m_klist[100];
    __shared__ int m_kn;
    __shared__ float m_cf[100 * NK];
    __shared__ float m_f4[4];
    if (tid == 0) m_kn = 0;
    __syncthreads();
    if (tid < mb) {
      int p = pos_list[b * 128 + tid];
      if (pmi[b * NP + p] == gi) {
        int slot = atomicAdd(&m_kn, 1);
        m_klist[slot] = p;
      }
    }
    __syncthreads();
    int kn = m_kn;
    if (kn == 0) return;   // uniform exit

    const float* g = box_gt + (b * NOBJ + gi) * 4;
    float bx1 = g[0], by1 = g[1], bx2 = g[2], by2 = g[3];
    float ax = bx1 * 138.f, bx = bx2 * 138.f;
    float x1 = fminf(ax, bx), x2 = fmaxf(ax, bx);
    x1 = fmaxf(x1 - 1.f, 0.f); x2 = fminf(x2 + 1.f, 138.f);
    float ay = by1 * 138.f, by_ = by2 * 138.f;
    float y1 = fminf(ay, by_), y2 = fmaxf(ay, by_);
    y1 = fmaxf(y1 - 1.f, 0.f); y2 = fminf(y2 + 1.f, 138.f);
    float inv = 1.f / ((bx2 - bx1) * (by2 - by1));
    int xs = (int)ceilf(x1), xe = (int)ceilf(x2);
    int ys = (int)ceilf(y1), ye = (int)ceilf(y2);
    if (xe < xs) xe = xs;
    if (ye < ys) ye = ys;

    for (int i = tid; i < kn * NK; i += 256) {
      int kk = i >> 5, c = i & 31;
      m_cf[i] = coef_p[((size_t)(b * NP) + m_klist[kk]) * NK + c];
    }
    __syncthreads();

    float knf = (float)kn;
    const float* protoB = proto_p + (size_t)b * NPX * NK;
    const unsigned char* dpl = dmp + (size_t)(b * NOBJ + gi) * NPX;

    float lsum = 0.f;
    for (int y = ys + chunk * 4 + wv; y < ye; y += 64) {
      const float* rowp = protoB + (size_t)y * PWD * NK;
      const unsigned char* rowg = dpl + y * PWD;
      for (int x = xs + lane; x < xe; x += 64) {
        const float4* pr = (const float4*)(rowp + (size_t)x * NK);
        float4 a0 = pr[0], a1 = pr[1], a2 = pr[2], a3 = pr[3];
        float4 a4 = pr[4], a5 = pr[5], a6 = pr[6], a7 = pr[7];
        int gbit = rowg[x];
        float base = gbit ? C_POS : C_NEGLO;
        float acc = -knf * base;    // fold out-of-rect constants per pixel
        for (int kk = 0; kk < kn; ++kk) {
          const float4* cf = (const float4*)&m_cf[kk * NK];
          float4 c0 = cf[0], c1 = cf[1], c2 = cf[2], c3 = cf[3];
          float4 c4 = cf[4], c5 = cf[5], c6 = cf[6], c7 = cf[7];
          float dot =
              a0.x*c0.x + a0.y*c0.y + a0.z*c0.z + a0.w*c0.w +
              a1.x*c1.x + a1.y*c1.y + a1.z*c1.z + a1.w*c1.w +
              a2.x*c2.x + a2.y*c2.y + a2.z*c2.z + a2.w*c2.w +
              a3.x*c3.x + a3.y*c3.y + a3.z*c3.z + a3.w*c3.w +
              a4.x*c4.x + a4.y*c4.y + a4.z*c4.z + a4.w*c4.w +
              a5.x*c5.x + a5.y*c5.y + a5.z*c5.z + a5.w*c5.w +
              a6.x*c6.x + a6.y*c6.y + a6.z*c6.z + a6.w*c6.w +
              a7.x*c7.x + a7.y*c7.y + a7.z*c7.z + a7.w*c7.w;
          float l = dot;
          float el = __expf(-fabsf(l));
          float sp = fmaxf(l, 0.f) + __logf(1.f + el);
          float t1 = fminf(sp - l, C_POS);
          float t2 = fminf(fmaxf(sp, C_NEGLO), C_NEGHI);
          acc += gbit ? t1 : t2;
        }
        lsum += acc;
      }
    }

    lsum = wave_sum(lsum);
    if (lane == 0) m_f4[wv] = lsum;
    __syncthreads();
    if (tid == 0) {
      float L = m_f4[0] + m_f4[1] + m_f4[2] + m_f4[3];
      if (chunk == 0) {
        int Gt = gtot[bg];
        L += knf * (C_POS * (float)Gt + C_NEGLO * (float)(NPX - Gt));
      }
      atomicAdd(&asp[128 + (bg & 7) * 16], L * inv * scale_arr[b]);
    }
  }
}

__global__ void finalize_kernel(const float* accum, const float* asp, float* out) {
  float c1 = 0.f, c2 = 0.f;
  #pragma unroll
  for (int i = 0; i < 8; i++) { c1 += asp[i * 16]; c2 += asp[128 + i * 16]; }
  out[0] = 1.5f * accum[0] + c1 + c2 * (6.125f / (138.f * 138.f));
}

extern "C" void kernel_launch(void* const* d_in, const int* in_sizes, int n_in,
                              void* d_out, int out_size, void* d_ws, size_t ws_size,
                              hipStream_t stream) {
  const float* class_p  = (const float*)d_in[0];
  const float* box_p    = (const float*)d_in[1];
  const float* coef_p   = (const float*)d_in[2];
  const float* proto_p  = (const float*)d_in[3];
  const float* priors   = (const float*)d_in[4];
  const float* box_gt   = (const float*)d_in[5];
  const float* mask_gt  = (const float*)d_in[6];
  const int*   class_gt = (const int*)d_in[7];

  char* ws = (char*)d_ws;
  float* prior_max = (float*)(ws + 0);                 // NB*NP f32 = 615936 B
  int*   prior_arg = (int*)(ws + 615936);              // NB*NP i32
  int*   conf      = (int*)(ws + 1231872);             // NB*NP i32
  float* marks     = (float*)(ws + 1847808);           // NB*NP f32 (aliases blkfmax)
  unsigned long long* blkfmax = (unsigned long long*)marks; // dead until mark (P2)
  unsigned char* dmp = (unsigned char*)(ws + 2463744); // NB*NOBJ*NPX u8 = 1218816
  int*   pos_list  = (int*)(ws + 3682560);             // NB*128 i32 = 4096
  int*   npos_arr  = (int*)(ws + 3686656);             // NB i32
  int*   nneg_arr  = (int*)(ws + 3686688);             // NB i32
  float* scale_arr = (float*)(ws + 3686720);           // NB f32
  float* blkloss   = (float*)(ws + 3686752);           // NB*NBLK f32 = 2432
  int*   blkcnt    = (int*)(ws + 3689184);             // NB*NBLK i32 = 2432
  // ---- memset region: accum(64) + gtot(256) + asp(1024) = 1344 B ----
  float* accum     = (float*)(ws + 3691616);
  int*   gtot      = (int*)(ws + 3691680);
  float* asp       = (float*)(ws + 3691936);
  (void)in_sizes; (void)n_in; (void)out_size; (void)ws_size;

  hipMemsetAsync((void*)accum, 0, 1344, stream);

  p0_match_resize<<<NB * NBLK + 368, 256, 0, stream>>>(
      priors, box_gt, mask_gt, prior_max, prior_arg, blkfmax, dmp, gtot);
  {
    dim3 g(NBLK, NB);
    conf_kernel<<<g, 256, 0, stream>>>(priors, box_gt, class_gt, box_p,
                                       prior_max, prior_arg, blkfmax, conf, blkcnt, blkloss);
  }
  p2_scatter_mark<<<NB * NBLK + MGRID, 256, 0, stream>>>(
      class_p, conf, blkcnt, blkloss, pos_list, npos_arr, nneg_arr, scale_arr,
      marks, accum, asp);
  p3_select_maskloss<<<NB + NB * NOBJ * 16, 256, 0, stream>>>(
      proto_p, coef_p, box_gt, prior_arg, dmp, pos_list, npos_arr, nneg_arr,
      gtot, scale_arr, marks, asp);
  finalize_kernel<<<1, 1, 0, stream>>>(accum, asp, (float*)d_out);
}

// Round 9
// 232.739 us; speedup vs baseline: 2.2869x; 1.0488x over previous
//
#include <hip/hip_runtime.h>
#include <math.h>

#define NB 8
#define NP 19248
#define NC 81
#define NOBJ 8
#define NK 32
#define PHD 138
#define PWD 138
#define NPX (PHD * PWD)   // 19044
#define IH 550
#define IW 550
#define NBLK 76           // ceil(NP/256)
#define MROWG 9624        // (NB*NP)/16 row-groups for mark
#define MGRID 1203        // mark virtual grid: 8 row-groups per block
#define BFSTRIDE 80       // blkfmax row stride (u64)
#define NOYG 46           // resize oy-groups (138 = 46*3)
#define RBLKS (16 * NOYG) // 736 resize blocks

__device__ __forceinline__ float wave_sum(float v) {
  #pragma unroll
  for (int o = 32; o >= 1; o >>= 1) v += __shfl_xor(v, o);
  return v;
}
__device__ __forceinline__ int wave_sum_i(int v) {
  #pragma unroll
  for (int o = 32; o >= 1; o >>= 1) v += __shfl_xor(v, o);
  return v;
}

// ============ P0: resize (blocks 0..735) || match1 (blocks 736..1343) ============
// Resize first: its long-latency waves launch earliest; match1's quick blocks fill
// behind. Resize: fold 3 oy-rows/block (2x blocks vs r8) + x2-unroll-2 (16 float2
// in flight before FMA) — attacks the Little's-law limit (r8: 4KB/wave -> 1.1TB/s).
// All reductions end in plain stores (no atomics, no memset prerequisites).
__global__ __launch_bounds__(256) void p0_match_resize(
    const float* __restrict__ priors, const float* __restrict__ box_gt,
    const float* __restrict__ mask_gt,
    float* __restrict__ prior_max, int* __restrict__ prior_arg,
    unsigned long long* __restrict__ blkfmax,
    unsigned char* __restrict__ dmp, int* __restrict__ gtot2)
{
  const int bid = blockIdx.x, tid = threadIdx.x;
  const int lane = tid & 63, wv = tid >> 6;

  if (bid < RBLKS) {
    // ---- resize: one plane per wave, 3 output rows; ones-count -> gtot2 slot ----
    int pg = bid & 15;           // plane group 0..15
    int oyg = bid >> 4;          // 0..45
    int bn = pg * 4 + wv;        // plane 0..63
    __shared__ float r_tmp[4][IW];
    __shared__ float r_wx[PWD][9];
    __shared__ float r_wsx[PWD];
    __shared__ int   r_xlo[PWD];
    const float ks = (float)IH / (float)PHD;
    if (tid < PWD) {
      int ox = tid;
      float sx = (ox + 0.5f) * ks - 0.5f;
      int xlo = (int)ceilf(sx - ks); if (xlo < 0) xlo = 0;
      int xhi = (int)floorf(sx + ks); if (xhi > IW - 1) xhi = IW - 1;
      int nx = xhi - xlo;
      float wsx = 0.f;
      #pragma unroll
      for (int i = 0; i < 8; i++) {
        float w = (i <= nx) ? fmaxf(0.f, 1.f - fabsf(sx - (float)(xlo + i)) / ks) : 0.f;
        r_wx[ox][i] = w; wsx += w;
      }
      r_xlo[ox] = xlo;
      r_wsx[ox] = wsx;
    }
    __syncthreads();
    const float* mg = mask_gt + (size_t)bn * (IH * IW);
    int ones = 0;
    for (int q = 0; q < 3; ++q) {
      int oy = oyg * 3 + q;      // 0..137
      float sy = (oy + 0.5f) * ks - 0.5f;
      int ylo = (int)ceilf(sy - ks); if (ylo < 0) ylo = 0;
      int yhi = (int)floorf(sy + ks); if (yhi > IH - 1) yhi = IH - 1;
      int ny = yhi - ylo;
      float wy[8]; float wsy = 0.f;
      #pragma unroll
      for (int j = 0; j < 8; j++) {
        float w = (j <= ny) ? fmaxf(0.f, 1.f - fabsf(sy - (float)(ylo + j)) / ks) : 0.f;
        wy[j] = w; wsy += w;
      }
      const float* rowp[8];
      #pragma unroll
      for (int j = 0; j < 8; j++) {
        int y = ylo + j; if (y > IH - 1) y = IH - 1;
        rowp[j] = mg + (size_t)y * IW;
      }
      // vertical pass, unroll x2 by 2: 16 float2 loads issued before accumulation
      for (int x2 = lane; x2 < IW / 2; x2 += 128) {
        int x2b = x2 + 64;
        bool hb = x2b < IW / 2;
        float2 va[8], vb[8];
        #pragma unroll
        for (int j = 0; j < 8; j++) {
          va[j] = *(const float2*)(rowp[j] + 2 * x2);
          if (hb) vb[j] = *(const float2*)(rowp[j] + 2 * x2b);
          else { vb[j].x = 0.f; vb[j].y = 0.f; }
        }
        float ax = 0.f, ay = 0.f, bx_ = 0.f, by_ = 0.f;
        #pragma unroll
        for (int j = 0; j < 8; j++) {
          ax  += wy[j] * va[j].x;
          ay  += wy[j] * va[j].y;
          bx_ += wy[j] * vb[j].x;
          by_ += wy[j] * vb[j].y;
        }
        r_tmp[wv][2 * x2]     = ax;
        r_tmp[wv][2 * x2 + 1] = ay;
        if (hb) {
          r_tmp[wv][2 * x2b]     = bx_;
          r_tmp[wv][2 * x2b + 1] = by_;
        }
      }
      __syncthreads();
      unsigned char* op = dmp + (size_t)bn * NPX + (size_t)oy * PWD;
      for (int ox = lane; ox < PWD; ox += 64) {
        int xlo = r_xlo[ox];
        float vsum = 0.f;
        #pragma unroll
        for (int i = 0; i < 8; i++) {
          int xi = xlo + i; if (xi > IW - 1) xi = IW - 1;
          vsum += r_wx[ox][i] * r_tmp[wv][xi];
        }
        int bit = (vsum > 0.5f * wsy * r_wsx[ox]) ? 1 : 0;
        op[ox] = (unsigned char)bit;
        ones += bit;
      }
      __syncthreads();
    }
    ones = wave_sum_i(ones);
    if (lane == 0) gtot2[bn * NOYG + oyg] = ones;   // plain store, no init needed
  } else {
    // ---- match1: per-prior max/arg; per-gt per-BLOCK max -> plain store ----
    int mb = bid - RBLKS;        // 0..607
    int b = mb / NBLK, bx = mb - b * NBLK;
    int p = bx * 256 + tid;
    __shared__ float gx1[NOBJ], gy1[NOBJ], gx2[NOBJ], gy2[NOBJ], garea[NOBJ];
    __shared__ unsigned long long s_red[4][NOBJ];
    if (tid < NOBJ) {
      const float* g = box_gt + (b * NOBJ + tid) * 4;
      float x1 = g[0], y1 = g[1], x2 = g[2], y2 = g[3];
      gx1[tid] = x1; gy1[tid] = y1; gx2[tid] = x2; gy2[tid] = y2;
      garea[tid] = (x2 - x1) * (y2 - y1);
    }
    __syncthreads();
    bool act = p < NP;
    float dx1 = 0, dy1 = 0, dx2 = 0, dy2 = 0, darea = 1.f;
    if (act) {
      const float* pr = priors + p * 4;
      float cx = pr[0], cy = pr[1], w = pr[2], h = pr[3];
      dx1 = cx - w * 0.5f; dy1 = cy - h * 0.5f;
      dx2 = cx + w * 0.5f; dy2 = cy + h * 0.5f;
      darea = (dx2 - dx1) * (dy2 - dy1);
    }
    float pmax = -1.f; int parg = 0;
    unsigned long long pk[NOBJ];
    #pragma unroll
    for (int j = 0; j < NOBJ; j++) {
      float ix = fmaxf(fminf(gx2[j], dx2) - fmaxf(gx1[j], dx1), 0.f);
      float iy = fmaxf(fminf(gy2[j], dy2) - fmaxf(gy1[j], dy1), 0.f);
      float inter = ix * iy;
      float iou = inter / (garea[j] + darea - inter);
      if (j == 0) { pmax = iou; parg = 0; }
      else if (iou > pmax) { pmax = iou; parg = j; }   // strict > tie-break
      pk[j] = act ? ((((unsigned long long)__float_as_uint(iou)) << 32)
                     | (unsigned long long)(0x7fffffffu - (unsigned)p))
                  : 0ull;
    }
    if (act) {
      prior_max[b * NP + p] = pmax;
      prior_arg[b * NP + p] = parg;
    }
    #pragma unroll
    for (int j = 0; j < NOBJ; j++) {
      unsigned long long v = pk[j];
      #pragma unroll
      for (int o = 32; o >= 1; o >>= 1) {
        unsigned long long ov = __shfl_xor(v, o);
        if (ov > v) v = ov;
      }
      if (lane == 0) s_red[wv][j] = v;
    }
    __syncthreads();
    if (tid < NOBJ) {
      unsigned long long v = s_red[0][tid];
      #pragma unroll
      for (int w = 1; w < 4; w++) { unsigned long long t = s_red[w][tid]; if (t > v) v = t; }
      blkfmax[(size_t)(b * NOBJ + tid) * BFSTRIDE + bx] = v;
    }
  }
}

// ============ P1: conf (608 blocks) ============
__global__ __launch_bounds__(256) void conf_kernel(
    const float* __restrict__ priors, const float* __restrict__ box_gt,
    const int* __restrict__ class_gt, const float* __restrict__ box_p,
    const float* __restrict__ prior_max, int* __restrict__ prior_arg,
    const unsigned long long* __restrict__ blkfmax,
    int* __restrict__ conf, int* __restrict__ blkcnt, float* __restrict__ blkloss)
{
  int b = blockIdx.y, bx = blockIdx.x, tid = threadIdx.x;
  int p = bx * 256 + tid;
  int lane = tid & 63, wid = tid >> 6;
  __shared__ int s_fi[NOBJ];
  __shared__ float lbw[4];
  __shared__ int pcw[4];
  #pragma unroll
  for (int jj = 0; jj < 2; jj++) {
    int j = wid * 2 + jj;
    const unsigned long long* bp_ = blkfmax + (size_t)(b * NOBJ + j) * BFSTRIDE;
    unsigned long long v = (lane < NBLK) ? bp_[lane] : 0ull;
    if (lane + 64 < NBLK) { unsigned long long t = bp_[lane + 64]; if (t > v) v = t; }
    #pragma unroll
    for (int o = 32; o >= 1; o >>= 1) {
      unsigned long long ov = __shfl_xor(v, o);
      if (ov > v) v = ov;
    }
    if (lane == 0) s_fi[j] = 0x7fffffff - (int)(v & 0xffffffffull);
  }
  __syncthreads();
  float lb = 0.f;
  bool flag = false;
  if (p < NP) {
    float m = prior_max[b * NP + p];
    int j = prior_arg[b * NP + p];
    int ov = -1;
    #pragma unroll
    for (int jj = 0; jj < NOBJ; jj++)
      if (p == s_fi[jj]) ov = jj;      // later j wins
    if (ov >= 0) { m = 2.0f; j = ov; prior_arg[b * NP + p] = ov; }
    int cf = class_gt[b * NOBJ + j] + 1;
    if (m < 0.5f) cf = -1;
    if (m < 0.4f) cf = 0;
    conf[b * NP + p] = cf;
    flag = cf > 0;
    if (flag) {
      const float* g = box_gt + (b * NOBJ + j) * 4;
      float x1 = g[0], y1 = g[1], x2 = g[2], y2 = g[3];
      const float* pr = priors + p * 4;
      float pcx = pr[0], pcy = pr[1], prw = pr[2], prh = pr[3];
      float o4[4];
      o4[0] = ((x1 + x2) * 0.5f - pcx) / (0.1f * prw);
      o4[1] = ((y1 + y2) * 0.5f - pcy) / (0.1f * prh);
      o4[2] = logf((x2 - x1) / prw) / 0.2f;
      o4[3] = logf((y2 - y1) / prh) / 0.2f;
      const float* bp = box_p + (b * NP + p) * 4;
      #pragma unroll
      for (int c = 0; c < 4; c++) {
        float d = fabsf(bp[c] - o4[c]);
        lb += (d < 1.f) ? 0.5f * d * d : d - 0.5f;
      }
    }
  }
  unsigned long long bm = __ballot(flag);
  lb = wave_sum(lb);
  if (lane == 0) { lbw[wid] = lb; pcw[wid] = __popcll(bm); }
  __syncthreads();
  if (tid == 0) {
    blkloss[b * NBLK + bx] = lbw[0] + lbw[1] + lbw[2] + lbw[3];
    blkcnt[b * NBLK + bx] = pcw[0] + pcw[1] + pcw[2] + pcw[3];
  }
}

// ============ P2: scatter (blocks 0..607) || mark (blocks 608..1810) ============
__global__ __launch_bounds__(256) void p2_scatter_mark(
    const float* __restrict__ class_p, const int* __restrict__ conf,
    const int* __restrict__ blkcnt, const float* __restrict__ blkloss,
    int* __restrict__ pos_list, int* __restrict__ npos_arr,
    int* __restrict__ nneg_arr, float* __restrict__ scale_arr,
    float* __restrict__ marks, float* __restrict__ loss_b,
    float* __restrict__ markpart)
{
  const int bid = blockIdx.x, tid = threadIdx.x;
  const int lane = tid & 63, wid = tid >> 6;

  if (bid < NB * NBLK) {
    // ---- scatter: ordered compaction + per-batch totals + box-loss reduce ----
    int b = bid / NBLK, bx = bid - b * NBLK;
    __shared__ int s_pre;
    __shared__ int wc[4];
    if (tid < 64) {
      int s = 0;
      if (tid < bx) s += blkcnt[b * NBLK + tid];
      int t2 = tid + 64;
      if (t2 < bx) s += blkcnt[b * NBLK + t2];
      s = wave_sum_i(s);
      if (tid == 0) s_pre = s;
    }
    int p = bx * 256 + tid;
    bool flag = (p < NP) && (conf[b * NP + p] > 0);
    unsigned long long m = __ballot(flag);
    if (lane == 0) wc[wid] = __popcll(m);
    __syncthreads();
    int base = s_pre;
    for (int w = 0; w < wid; w++) base += wc[w];
    int idx = base + __popcll(m & ((1ull << lane) - 1ull));
    if (flag && idx < 128) pos_list[b * 128 + idx] = p;
    if (bx == NBLK - 1) {
      if (tid == 0) {
        int np = s_pre + wc[0] + wc[1] + wc[2] + wc[3];
        npos_arr[b] = np;
        int nn = 3 * np; if (nn > NP - 1) nn = NP - 1;
        nneg_arr[b] = nn;
        scale_arr[b] = (np > 100) ? (float)np / 100.0f : 1.0f;
      }
      if (tid < 64) {
        float s = (tid < NBLK) ? blkloss[b * NBLK + tid] : 0.f;
        if (tid + 64 < NBLK) s += blkloss[b * NBLK + tid + 64];
        s = wave_sum(s);
        if (tid == 0) loss_b[b] = s;   // plain store
      }
    }
  } else {
    // ---- mark: grid-stride LSE rows; block partial -> markpart (plain store) ----
    int mbid = bid - NB * NBLK;   // 0..1202
    int sub = lane & 15, grp = lane >> 4;
    __shared__ float sred[4];
    float acc1 = 0.f;
    for (int gblk = mbid; gblk < MROWG; gblk += MGRID) {
      int row = gblk * 16 + wid * 4 + grp;
      const float* cp = class_p + (size_t)row * NC;
      float v[6];
      #pragma unroll
      for (int k = 0; k < 6; k++) {
        int c = sub + 16 * k;
        v[k] = (c < NC) ? cp[c] : -INFINITY;
      }
      float m = v[0];
      #pragma unroll
      for (int k = 1; k < 6; k++) m = fmaxf(m, v[k]);
      #pragma unroll
      for (int o = 1; o < 16; o <<= 1) m = fmaxf(m, __shfl_xor(m, o));
      float s = 0.f;
      #pragma unroll
      for (int k = 0; k < 6; k++) s += __expf(v[k] - m);
      #pragma unroll
      for (int o = 1; o < 16; o <<= 1) s += __shfl_xor(s, o);
      float lse = m + __logf(s);
      if (sub == 0) {
        int cf = conf[row];
        marks[row] = (cf != 0) ? 0.f : (lse - v[0]);
        if (cf > 0) acc1 += lse - cp[cf];
      }
    }
    acc1 = wave_sum(acc1);
    if (lane == 0) sred[wid] = acc1;
    __syncthreads();
    if (tid == 0)
      markpart[mbid] = sred[0] + sred[1] + sred[2] + sred[3];
  }
}

// ============ P3: select (blocks 0..7) || maskloss (blocks 8..1031) ============
__global__ __launch_bounds__(256) void p3_select_maskloss(
    const float* __restrict__ proto_p, const float* __restrict__ coef_p,
    const float* __restrict__ box_gt, const int* __restrict__ pmi,
    const unsigned char* __restrict__ dmp, const int* __restrict__ pos_list,
    const int* __restrict__ npos_arr, const int* __restrict__ nneg_arr,
    const int* __restrict__ gtot2, const float* __restrict__ scale_arr,
    const float* __restrict__ marks, float* __restrict__ selpart,
    float* __restrict__ mlpart)
{
  const int bid = blockIdx.x, tid = threadIdx.x;
  const int lane = tid & 63, wv = tid >> 6;
  const float C_POS   = 16.11809565f;     // -log(1e-7)
  const float C_NEGHI = 15.94238515f;     // -log1p(-0.99999988f)
  const float C_NEGLO = 1.00000005e-07f;  // -log1p(-1e-7f)

  if (bid < NB) {
    // ---- select: per-batch top-k marks sum via bit-space binary search ----
    int b = bid;
    __shared__ unsigned s_lo, s_hi;
    __shared__ int s_i4[4];
    __shared__ float s_f4[4];
    float v[NBLK];
    #pragma unroll
    for (int i = 0; i < NBLK; i++) {
      int p = i * 256 + tid;
      v[i] = (p < NP) ? marks[b * NP + p] : 0.f;
    }
    int k = nneg_arr[b];
    if (tid == 0) { s_lo = 0u; s_hi = 0x7f800000u; }
    __syncthreads();
    while (true) {
      unsigned lo = s_lo, hi = s_hi;
      if (hi - lo <= 1u) break;
      unsigned mid = lo + ((hi - lo) >> 1);
      float fmid = __uint_as_float(mid);
      int cnt = 0;
      #pragma unroll
      for (int i = 0; i < NBLK; i++) cnt += (v[i] >= fmid) ? 1 : 0;
      cnt = wave_sum_i(cnt);
      if (lane == 0) s_i4[wv] = cnt;
      __syncthreads();
      if (tid == 0) {
        int tot = s_i4[0] + s_i4[1] + s_i4[2] + s_i4[3];
        if (tot >= k) s_lo = mid; else s_hi = mid;
      }
      __syncthreads();
    }
    float thr = __uint_as_float(s_lo);
    float s = 0.f;
    #pragma unroll
    for (int i = 0; i < NBLK; i++) if (v[i] >= thr) s += v[i];
    s = wave_sum(s);
    if (lane == 0) s_f4[wv] = s;
    __syncthreads();
    if (tid == 0) selpart[b] = s_f4[0] + s_f4[1] + s_f4[2] + s_f4[3];
  } else {
    // ---- maskloss: per-(box, row-chunk) rect-only f32 dot + folded constants ----
    int vb = bid - NB;         // 0..1023
    int bg = vb >> 4;          // 0..63 = b*NOBJ + gi
    int b = bg >> 3, gi = bg & 7;
    int chunk = vb & 15;
    int np = npos_arr[b];
    int mb = np < 100 ? np : 100;

    __shared__ int m_klist[100];
    __shared__ int m_kn, m_gt;
    __shared__ float m_cf[100 * NK];
    __shared__ float m_f4[4];
    if (tid == 0) m_kn = 0;
    __syncthreads();
    if (tid < mb) {
      int p = pos_list[b * 128 + tid];
      if (pmi[b * NP + p] == gi) {
        int slot = atomicAdd(&m_kn, 1);   // LDS atomic only
        m_klist[slot] = p;
      }
    }
    // chunk-0 blocks also reduce this plane's gt total from gtot2 partials
    if (chunk == 0 && tid >= 128 && tid < 192) {
      int l2 = tid - 128;
      int gv = (l2 < NOYG) ? gtot2[bg * NOYG + l2] : 0;
      gv = wave_sum_i(gv);
      if (l2 == 0) m_gt = gv;
    }
    __syncthreads();
    int kn = m_kn;
    if (kn == 0) {
      if (tid == 0) mlpart[vb] = 0.f;   // slot must be written (no memset)
      return;
    }

    const float* g = box_gt + (b * NOBJ + gi) * 4;
    float bx1 = g[0], by1 = g[1], bx2 = g[2], by2 = g[3];
    float ax = bx1 * 138.f, bx = bx2 * 138.f;
    float x1 = fminf(ax, bx), x2 = fmaxf(ax, bx);
    x1 = fmaxf(x1 - 1.f, 0.f); x2 = fminf(x2 + 1.f, 138.f);
    float ay = by1 * 138.f, by_ = by2 * 138.f;
    float y1 = fminf(ay, by_), y2 = fmaxf(ay, by_);
    y1 = fmaxf(y1 - 1.f, 0.f); y2 = fminf(y2 + 1.f, 138.f);
    float inv = 1.f / ((bx2 - bx1) * (by2 - by1));
    int xs = (int)ceilf(x1), xe = (int)ceilf(x2);
    int ys = (int)ceilf(y1), ye = (int)ceilf(y2);
    if (xe < xs) xe = xs;
    if (ye < ys) ye = ys;

    for (int i = tid; i < kn * NK; i += 256) {
      int kk = i >> 5, c = i & 31;
      m_cf[i] = coef_p[((size_t)(b * NP) + m_klist[kk]) * NK + c];
    }
    __syncthreads();

    float knf = (float)kn;
    const float* protoB = proto_p + (size_t)b * NPX * NK;
    const unsigned char* dpl = dmp + (size_t)(b * NOBJ + gi) * NPX;

    float lsum = 0.f;
    for (int y = ys + chunk * 4 + wv; y < ye; y += 64) {
      const float* rowp = protoB + (size_t)y * PWD * NK;
      const unsigned char* rowg = dpl + y * PWD;
      for (int x = xs + lane; x < xe; x += 64) {
        const float4* pr = (const float4*)(rowp + (size_t)x * NK);
        float4 a0 = pr[0], a1 = pr[1], a2 = pr[2], a3 = pr[3];
        float4 a4 = pr[4], a5 = pr[5], a6 = pr[6], a7 = pr[7];
        int gbit = rowg[x];
        float base = gbit ? C_POS : C_NEGLO;
        float acc = -knf * base;    // fold out-of-rect constants per pixel
        for (int kk = 0; kk < kn; ++kk) {
          const float4* cf = (const float4*)&m_cf[kk * NK];
          float4 c0 = cf[0], c1 = cf[1], c2 = cf[2], c3 = cf[3];
          float4 c4 = cf[4], c5 = cf[5], c6 = cf[6], c7 = cf[7];
          float dot =
              a0.x*c0.x + a0.y*c0.y + a0.z*c0.z + a0.w*c0.w +
              a1.x*c1.x + a1.y*c1.y + a1.z*c1.z + a1.w*c1.w +
              a2.x*c2.x + a2.y*c2.y + a2.z*c2.z + a2.w*c2.w +
              a3.x*c3.x + a3.y*c3.y + a3.z*c3.z + a3.w*c3.w +
              a4.x*c4.x + a4.y*c4.y + a4.z*c4.z + a4.w*c4.w +
              a5.x*c5.x + a5.y*c5.y + a5.z*c5.z + a5.w*c5.w +
              a6.x*c6.x + a6.y*c6.y + a6.z*c6.z + a6.w*c6.w +
              a7.x*c7.x + a7.y*c7.y + a7.z*c7.z + a7.w*c7.w;
          float l = dot;
          float el = __expf(-fabsf(l));
          float sp = fmaxf(l, 0.f) + __logf(1.f + el);
          float t1 = fminf(sp - l, C_POS);
          float t2 = fminf(fmaxf(sp, C_NEGLO), C_NEGHI);
          acc += gbit ? t1 : t2;
        }
        lsum += acc;
      }
    }

    lsum = wave_sum(lsum);
    if (lane == 0) m_f4[wv] = lsum;
    __syncthreads();
    if (tid == 0) {
      float L = m_f4[0] + m_f4[1] + m_f4[2] + m_f4[3];
      if (chunk == 0) {
        int Gt = m_gt;
        L += knf * (C_POS * (float)Gt + C_NEGLO * (float)(NPX - Gt));
      }
      mlpart[vb] = L * inv * scale_arr[b];   // plain store
    }
  }
}

// ============ P4: finalize — 256-thread reducer over all partial arrays ============
__global__ __launch_bounds__(256) void finalize_kernel(
    const float* __restrict__ loss_b, const float* __restrict__ markpart,
    const float* __restrict__ selpart, const float* __restrict__ mlpart,
    float* __restrict__ out)
{
  int tid = threadIdx.x, lane = tid & 63, wv = tid >> 6;
  __shared__ float sb[4], sc[4], sm[4];
  float cb = 0.f, cc = 0.f, cm = 0.f;
  if (tid < NB) { cb = loss_b[tid]; cc += selpart[tid]; }
  for (int i = tid; i < MGRID; i += 256) cc += markpart[i];
  for (int i = tid; i < NB * NOBJ * 16; i += 256) cm += mlpart[i];
  cb = wave_sum(cb); cc = wave_sum(cc); cm = wave_sum(cm);
  if (lane == 0) { sb[wv] = cb; sc[wv] = cc; sm[wv] = cm; }
  __syncthreads();
  if (tid == 0) {
    float b_ = sb[0] + sb[1] + sb[2] + sb[3];
    float c_ = sc[0] + sc[1] + sc[2] + sc[3];
    float m_ = sm[0] + sm[1] + sm[2] + sm[3];
    out[0] = 1.5f * b_ + c_ + m_ * (6.125f / (138.f * 138.f));
  }
}

extern "C" void kernel_launch(void* const* d_in, const int* in_sizes, int n_in,
                              void* d_out, int out_size, void* d_ws, size_t ws_size,
                              hipStream_t stream) {
  const float* class_p  = (const float*)d_in[0];
  const float* box_p    = (const float*)d_in[1];
  const float* coef_p   = (const float*)d_in[2];
  const float* proto_p  = (const float*)d_in[3];
  const float* priors   = (const float*)d_in[4];
  const float* box_gt   = (const float*)d_in[5];
  const float* mask_gt  = (const float*)d_in[6];
  const int*   class_gt = (const int*)d_in[7];

  char* ws = (char*)d_ws;
  float* prior_max = (float*)(ws + 0);                 // NB*NP f32 = 615936 B
  int*   prior_arg = (int*)(ws + 615936);              // NB*NP i32
  int*   conf      = (int*)(ws + 1231872);             // NB*NP i32
  float* marks     = (float*)(ws + 1847808);           // NB*NP f32 (aliases blkfmax)
  unsigned long long* blkfmax = (unsigned long long*)marks; // dead until mark (P2)
  unsigned char* dmp = (unsigned char*)(ws + 2463744); // NB*NOBJ*NPX u8 = 1218816
  int*   pos_list  = (int*)(ws + 3682560);             // NB*128 i32 = 4096
  int*   npos_arr  = (int*)(ws + 3686656);             // NB i32 = 32
  int*   nneg_arr  = (int*)(ws + 3686688);             // NB i32 = 32
  float* scale_arr = (float*)(ws + 3686720);           // NB f32 = 32
  float* blkloss   = (float*)(ws + 3686752);           // NB*NBLK f32 = 2432
  int*   blkcnt    = (int*)(ws + 3689184);             // NB*NBLK i32 = 2432
  float* loss_b    = (float*)(ws + 3691616);           // NB f32 = 32
  int*   gtot2     = (int*)(ws + 3691648);             // 64*46 i32 = 11776
  float* markpart  = (float*)(ws + 3703424);           // 1203 f32 = 4812
  float* selpart   = (float*)(ws + 3708236);           // NB f32 = 32
  float* mlpart    = (float*)(ws + 3708268);           // 1024 f32 = 4096
  (void)in_sizes; (void)n_in; (void)out_size; (void)ws_size;

  // No memset: every partial slot is written unconditionally by its producer.

  p0_match_resize<<<RBLKS + NB * NBLK, 256, 0, stream>>>(
      priors, box_gt, mask_gt, prior_max, prior_arg, blkfmax, dmp, gtot2);
  {
    dim3 g(NBLK, NB);
    conf_kernel<<<g, 256, 0, stream>>>(priors, box_gt, class_gt, box_p,
                                       prior_max, prior_arg, blkfmax, conf, blkcnt, blkloss);
  }
  p2_scatter_mark<<<NB * NBLK + MGRID, 256, 0, stream>>>(
      class_p, conf, blkcnt, blkloss, pos_list, npos_arr, nneg_arr, scale_arr,
      marks, loss_b, markpart);
  p3_select_maskloss<<<NB + NB * NOBJ * 16, 256, 0, stream>>>(
      proto_p, coef_p, box_gt, prior_arg, dmp, pos_list, npos_arr, nneg_arr,
      gtot2, scale_arr, marks, selpart, mlpart);
  finalize_kernel<<<1, 256, 0, stream>>>(loss_b, markpart, selpart, mlpart,
                                         (float*)d_out);
}